// Round 2
// baseline (699.546 us; speedup 1.0000x reference)
//
#include <hip/hip_runtime.h>
#include <math.h>

// Problem constants
#define BB 4
#define VV 8192
#define EE 256
#define HH 8
#define KK 6
#define DH 32
#define NP (BB*VV)          // 32768 points total

// ---------------- workspace layout (bytes) ----------------
// xv4      : float4[NP]            @ 0          (524288)
// knn_idx  : int[NP*6]             @ 524288     (786432)
// xw_sum   : float[NP]             @ 1310720    (131072)
// xw_cnt   : float[NP]             @ 1441792    (131072)
// XQKV     : float[NP*768]         @ 1572864    (100663296)
// attn_out : float[NP*256]         @ 102236160  (33554432)
// total ~135.8 MB

#define OFF_XV4   0
#define OFF_KNN   524288
#define OFF_XWS   1310720
#define OFF_XWC   1441792
#define OFF_XQKV  1572864
#define OFF_ATTN  102236160

// lexicographic (dist, idx) compare: matches jax.lax.top_k tie-break (lower index wins)
#define LT(da,ia,db,ib) ((da)<(db) || ((da)==(db) && (ia)<(ib)))

#define INSERT6(dist,j) \
  if (LT(dist,j,d5,i5)) { \
    if (LT(dist,j,d4,i4)) { d5=d4;i5=i4; \
      if (LT(dist,j,d3,i3)) { d4=d3;i4=i3; \
        if (LT(dist,j,d2,i2)) { d3=d2;i3=i2; \
          if (LT(dist,j,d1,i1)) { d2=d1;i2=i1; \
            if (LT(dist,j,d0,i0)) { d1=d0;i1=i0; d0=dist;i0=j; } \
            else { d1=dist;i1=j; } \
          } else { d2=dist;i2=j; } \
        } else { d3=dist;i3=j; } \
      } else { d4=dist;i4=j; } \
    } else { d5=dist;i5=j; } \
  }

// ---------------- prep: pack xyz+sq, zero scatter accumulators ----------------
__global__ void prep_kernel(const float* __restrict__ xv, float4* __restrict__ xv4,
                            float* __restrict__ xw_sum, float* __restrict__ xw_cnt) {
  int i = blockIdx.x * blockDim.x + threadIdx.x;
  if (i >= NP) return;
  float x0 = xv[i*3+0], x1 = xv[i*3+1], x2 = xv[i*3+2];
  // exact fp32 op order of the reference: ((x0*x0 + x1*x1) + x2*x2), no FMA contraction
  float sq = __fadd_rn(__fadd_rn(__fmul_rn(x0,x0), __fmul_rn(x1,x1)), __fmul_rn(x2,x2));
  xv4[i] = make_float4(x0, x1, x2, sq);
  xw_sum[i] = 0.f;
  xw_cnt[i] = 0.f;
}

// ---------------- brute-force KNN: 8 threads per query, merge in LDS ----------------
__global__ __launch_bounds__(256) void knn_kernel(const float4* __restrict__ xv4,
                                                  int* __restrict__ knn_idx) {
  __shared__ float md[32][49];
  __shared__ int   mi[32][49];
  int tid = threadIdx.x;
  int qlocal = tid >> 3;          // 0..31 queries per block
  int c = tid & 7;                // candidate chunk 0..7
  int q = blockIdx.x * 32 + qlocal;   // global point (blocks never straddle batches: 8192%32==0)
  int b = q / VV;
  int base = b * VV;
  float4 me = xv4[q];
  float sqq = me.w;

  float d0=INFINITY,d1=INFINITY,d2=INFINITY,d3=INFINITY,d4=INFINITY,d5=INFINITY;
  int   i0=0x7fffffff,i1=0x7fffffff,i2=0x7fffffff,i3=0x7fffffff,i4=0x7fffffff,i5=0x7fffffff;

  for (int it = 0; it < VV/8; ++it) {
    int j = c + (it << 3);
    float4 p = xv4[base + j];
    // reference fp32 semantics: d = (sq_v + sq_w) - 2*dot, dot = ((x0*y0 + x1*y1) + x2*y2)
    float dot  = __fadd_rn(__fadd_rn(__fmul_rn(me.x,p.x), __fmul_rn(me.y,p.y)), __fmul_rn(me.z,p.z));
    float dist = __fsub_rn(__fadd_rn(sqq, p.w), __fmul_rn(2.0f, dot));
    INSERT6(dist, j);
  }

  int o = c * 6;
  md[qlocal][o+0]=d0; mi[qlocal][o+0]=i0;
  md[qlocal][o+1]=d1; mi[qlocal][o+1]=i1;
  md[qlocal][o+2]=d2; mi[qlocal][o+2]=i2;
  md[qlocal][o+3]=d3; mi[qlocal][o+3]=i3;
  md[qlocal][o+4]=d4; mi[qlocal][o+4]=i4;
  md[qlocal][o+5]=d5; mi[qlocal][o+5]=i5;
  __syncthreads();

  if (tid < 32) {
    float d0=INFINITY,d1=INFINITY,d2=INFINITY,d3=INFINITY,d4=INFINITY,d5=INFINITY;
    int   i0=0x7fffffff,i1=0x7fffffff,i2=0x7fffffff,i3=0x7fffffff,i4=0x7fffffff,i5=0x7fffffff;
    for (int t = 0; t < 48; ++t) {
      float dist = md[tid][t];
      int   j    = mi[tid][t];
      INSERT6(dist, j);
    }
    int q2 = blockIdx.x * 32 + tid;
    knn_idx[q2*6+0]=i0; knn_idx[q2*6+1]=i1; knn_idx[q2*6+2]=i2;
    knn_idx[q2*6+3]=i3; knn_idx[q2*6+4]=i4; knn_idx[q2*6+5]=i5;
  }
}

// ---------------- fp32 tiled GEMM: C[m,n] = sum_k A[m,k]*B[n,k] (+R), row-major ----------------
__global__ __launch_bounds__(256) void gemm64(const float* __restrict__ A,
                                              const float* __restrict__ Bm,
                                              float* __restrict__ C,
                                              const float* __restrict__ R,
                                              int M, int N, int Kd,
                                              int lda, int ldb, int ldc) {
  __shared__ __align__(16) float As[32][64];
  __shared__ __align__(16) float Bs[32][64];
  int tid = threadIdx.x;
  int bm = blockIdx.x * 64, bn = blockIdx.y * 64;
  int tx = tid & 15, ty = tid >> 4;
  int arow = tid >> 3;     // 0..31
  int acol4 = tid & 7;     // float4 index 0..7

  float acc[4][4] = {};

  for (int k0 = 0; k0 < Kd; k0 += 32) {
    float4 a0 = *(const float4*)&A[(size_t)(bm + arow)      * lda + k0 + acol4*4];
    float4 a1 = *(const float4*)&A[(size_t)(bm + arow + 32) * lda + k0 + acol4*4];
    float4 b0 = *(const float4*)&Bm[(size_t)(bn + arow)      * ldb + k0 + acol4*4];
    float4 b1 = *(const float4*)&Bm[(size_t)(bn + arow + 32) * ldb + k0 + acol4*4];
    __syncthreads();
    As[acol4*4+0][arow] = a0.x; As[acol4*4+1][arow] = a0.y;
    As[acol4*4+2][arow] = a0.z; As[acol4*4+3][arow] = a0.w;
    As[acol4*4+0][arow+32] = a1.x; As[acol4*4+1][arow+32] = a1.y;
    As[acol4*4+2][arow+32] = a1.z; As[acol4*4+3][arow+32] = a1.w;
    Bs[acol4*4+0][arow] = b0.x; Bs[acol4*4+1][arow] = b0.y;
    Bs[acol4*4+2][arow] = b0.z; Bs[acol4*4+3][arow] = b0.w;
    Bs[acol4*4+0][arow+32] = b1.x; Bs[acol4*4+1][arow+32] = b1.y;
    Bs[acol4*4+2][arow+32] = b1.z; Bs[acol4*4+3][arow+32] = b1.w;
    __syncthreads();
#pragma unroll
    for (int kk = 0; kk < 32; ++kk) {
      float4 av = *(const float4*)&As[kk][ty*4];
      float4 bv = *(const float4*)&Bs[kk][tx*4];
      acc[0][0] += av.x*bv.x; acc[0][1] += av.x*bv.y; acc[0][2] += av.x*bv.z; acc[0][3] += av.x*bv.w;
      acc[1][0] += av.y*bv.x; acc[1][1] += av.y*bv.y; acc[1][2] += av.y*bv.z; acc[1][3] += av.y*bv.w;
      acc[2][0] += av.z*bv.x; acc[2][1] += av.z*bv.y; acc[2][2] += av.z*bv.z; acc[2][3] += av.z*bv.w;
      acc[3][0] += av.w*bv.x; acc[3][1] += av.w*bv.y; acc[3][2] += av.w*bv.z; acc[3][3] += av.w*bv.w;
    }
  }

#pragma unroll
  for (int i2 = 0; i2 < 4; ++i2) {
    int row = bm + ty*4 + i2;
    int col = bn + tx*4;
    float4 out;
    out.x = acc[i2][0]; out.y = acc[i2][1]; out.z = acc[i2][2]; out.w = acc[i2][3];
    if (R) {
      float4 rr = *(const float4*)&R[(size_t)row * ldc + col];
      out.x += rr.x; out.y += rr.y; out.z += rr.z; out.w += rr.w;
    }
    *(float4*)&C[(size_t)row * ldc + col] = out;
  }
}

// ---------------- per-point attention: one wave per point ----------------
__global__ __launch_bounds__(256) void attn_kernel(const float* __restrict__ XQKV,
                                                   const int* __restrict__ knn_idx,
                                                   float* __restrict__ attn_out,
                                                   float* __restrict__ xw_sum,
                                                   float* __restrict__ xw_cnt) {
  int p = blockIdx.x * 4 + (threadIdx.x >> 6);   // point id 0..32767
  int lane = threadIdx.x & 63;
  int b = p >> 13;                 // /8192
  size_t gbase = (size_t)b << 13;  // b*V
  size_t prow = (size_t)p * 768;

  float4 q4 = *(const float4*)&XQKV[prow + lane*4];
  float4 self4 = *(const float4*)&XQKV[prow + 512 + lane*4];

  int idx[KK];
#pragma unroll
  for (int j = 0; j < KK; ++j) idx[j] = knn_idx[p*KK + j];

  float4 k4[KK], v4[KK];
#pragma unroll
  for (int j = 0; j < KK; ++j) {
    size_t r = (gbase + idx[j]) * 768;
    k4[j] = *(const float4*)&XQKV[r + 256 + lane*4];
    v4[j] = *(const float4*)&XQKV[r + 512 + lane*4];
  }

  // scores: per-head dot over 32 dims (8 lanes/head, 4 dims/lane)
  float s[KK];
#pragma unroll
  for (int j = 0; j < KK; ++j) {
    float t = q4.x*k4[j].x + q4.y*k4[j].y + q4.z*k4[j].z + q4.w*k4[j].w;
    t += __shfl_xor(t, 1);
    t += __shfl_xor(t, 2);
    t += __shfl_xor(t, 4);
    s[j] = t * 0.17677669529663687f;   // 1/sqrt(32)
  }

  // softmax over K=6 (lane-local, uniform within head group)
  float m = s[0];
#pragma unroll
  for (int j = 1; j < KK; ++j) m = fmaxf(m, s[j]);
  float e[KK], denom = 0.f;
#pragma unroll
  for (int j = 0; j < KK; ++j) { e[j] = expf(s[j] - m); denom += e[j]; }
  float inv = 1.0f / denom;
#pragma unroll
  for (int j = 0; j < KK; ++j) e[j] *= inv;

  // output: sum_j attn_j * (XV[idx_j] - XV[self])
  float4 o = make_float4(0.f, 0.f, 0.f, 0.f);
#pragma unroll
  for (int j = 0; j < KK; ++j) {
    float a = e[j];
    o.x += a * (v4[j].x - self4.x);
    o.y += a * (v4[j].y - self4.y);
    o.z += a * (v4[j].z - self4.z);
    o.w += a * (v4[j].w - self4.w);
  }
  *(float4*)&attn_out[(size_t)p * 256 + lane*4] = o;

  // x_w scatter: mean over heads of attn, atomically accumulated at target index
#pragma unroll
  for (int j = 0; j < KK; ++j) {
    float t = e[j];
    t += __shfl_xor(t, 8);
    t += __shfl_xor(t, 16);
    t += __shfl_xor(t, 32);
    if (lane == 0) {
      atomicAdd(&xw_sum[gbase + idx[j]], t * 0.125f);
      atomicAdd(&xw_cnt[gbase + idx[j]], 1.0f);
    }
  }
}

// ---------------- finalize: xw_out = sum/(count+1) ----------------
__global__ void finalize_xw(const float* __restrict__ xw_sum,
                            const float* __restrict__ xw_cnt,
                            float* __restrict__ out) {
  int i = blockIdx.x * blockDim.x + threadIdx.x;
  if (i < NP) out[i] = xw_sum[i] / (xw_cnt[i] + 1.0f);
}

extern "C" void kernel_launch(void* const* d_in, const int* in_sizes, int n_in,
                              void* d_out, int out_size, void* d_ws, size_t ws_size,
                              hipStream_t stream) {
  const float* x     = (const float*)d_in[0];   // [B,V,E]
  const float* xv    = (const float*)d_in[1];   // [B,V,3]
  const float* w_in  = (const float*)d_in[2];   // [3E,E]
  const float* w_out = (const float*)d_in[3];   // [E,E]
  float* out = (float*)d_out;

  char* ws = (char*)d_ws;
  float4* xv4     = (float4*)(ws + OFF_XV4);
  int*    knn     = (int*)(ws + OFF_KNN);
  float*  xw_sum  = (float*)(ws + OFF_XWS);
  float*  xw_cnt  = (float*)(ws + OFF_XWC);
  float*  XQKV    = (float*)(ws + OFF_XQKV);
  float*  attn_o  = (float*)(ws + OFF_ATTN);

  prep_kernel<<<(NP + 255) / 256, 256, 0, stream>>>(xv, xv4, xw_sum, xw_cnt);
  knn_kernel<<<NP / 32, 256, 0, stream>>>(xv4, knn);
  // XQKV = x @ in_proj_w.T   [32768,768]
  gemm64<<<dim3(NP/64, 768/64), 256, 0, stream>>>(x, w_in, XQKV, nullptr,
                                                  NP, 768, EE, EE, EE, 768);
  attn_kernel<<<NP / 4, 256, 0, stream>>>(XQKV, knn, attn_o, xw_sum, xw_cnt);
  // x_out = attn_o @ out_proj_w.T + x   [32768,256]
  gemm64<<<dim3(NP/64, 256/64), 256, 0, stream>>>(attn_o, w_out, out, x,
                                                  NP, 256, EE, EE, EE, 256);
  finalize_xw<<<NP / 256, 256, 0, stream>>>(xw_sum, xw_cnt, out + (size_t)NP * EE);
}

// Round 3
// 642.437 us; speedup vs baseline: 1.0889x; 1.0889x over previous
//
#include <hip/hip_runtime.h>
#include <math.h>

// Problem constants
#define BB 4
#define VV 8192
#define EE 256
#define HH 8
#define KK 6
#define DH 32
#define NP (BB*VV)          // 32768 points total

// ---------------- workspace layout (bytes) ----------------
#define OFF_XV4   0
#define OFF_KNN   524288
#define OFF_XWS   1310720
#define OFF_XWC   1441792
#define OFF_XQKV  1572864
#define OFF_ATTN  102236160

// ---------------- prep: pack xyz+sq, zero scatter accumulators ----------------
__global__ void prep_kernel(const float* __restrict__ xv, float4* __restrict__ xv4,
                            float* __restrict__ xw_sum, float* __restrict__ xw_cnt) {
  int i = blockIdx.x * blockDim.x + threadIdx.x;
  if (i >= NP) return;
  float x0 = xv[i*3+0], x1 = xv[i*3+1], x2 = xv[i*3+2];
  // exact fp32 op order of the reference: ((x0*x0 + x1*x1) + x2*x2), no FMA contraction
  float sq = __fadd_rn(__fadd_rn(__fmul_rn(x0,x0), __fmul_rn(x1,x1)), __fmul_rn(x2,x2));
  xv4[i] = make_float4(x0, x1, x2, sq);
  xw_sum[i] = 0.f;
  xw_cnt[i] = 0.f;
}

// ---------------- brute-force KNN ----------------
// 4 lanes per query (each scans 2048 candidates). Block = 256 threads = 64
// queries x 4 chunk-waves; each wave has ONE chunk id c -> candidate address
// is wave-uniform (scalar load). Top-6 kept as packed u64 keys
// (sortable_dist<<32 | idx): u64 order == lexicographic (dist, idx) with
// lower index winning ties — exactly jax.lax.top_k semantics.

__device__ __forceinline__ unsigned long long pack_key(float dist, int j) {
  unsigned du = __float_as_uint(dist);
  du ^= (unsigned)((int)du >> 31) | 0x80000000u;   // monotone float->uint map
  return ((unsigned long long)du << 32) | (unsigned)j;
}

#define INS6(key) \
  if (key < k5) { \
    bool b4 = key < k4, b3 = key < k3, b2 = key < k2, b1 = key < k1, b0 = key < k0; \
    k5 = b4 ? k4 : key; \
    k4 = b4 ? (b3 ? k3 : key) : k4; \
    k3 = b3 ? (b2 ? k2 : key) : k3; \
    k2 = b2 ? (b1 ? k1 : key) : k2; \
    k1 = b1 ? (b0 ? k0 : key) : k1; \
    k0 = b0 ? key : k0; \
  }

__global__ __launch_bounds__(256) void knn_kernel(const float4* __restrict__ xv4,
                                                  int* __restrict__ knn_idx) {
  __shared__ unsigned long long mk[64][19];   // 18 used, +1 pad
  int tid = threadIdx.x;
  int qb = tid & 63;                                   // query within block
  int c = __builtin_amdgcn_readfirstlane(tid >> 6);    // chunk 0..3, wave-uniform
  int q = blockIdx.x * 64 + qb;
  int base = (blockIdx.x * 64) >> 13 << 13;            // batch base, provably uniform

  float4 me = xv4[q];
  float mx = me.x, my = me.y, mz = me.z, sqq = me.w;

  unsigned long long k0=~0ull,k1=~0ull,k2=~0ull,k3=~0ull,k4=~0ull,k5=~0ull;

  const float4* cand = xv4 + base + c * 2048;
#pragma unroll 4
  for (int it = 0; it < 2048; ++it) {
    float4 p = cand[it];                               // wave-uniform
    int j = c * 2048 + it;
    // reference fp32 semantics: d = (sq_v + sq_w) - 2*dot, dot = ((x0*y0 + x1*y1) + x2*y2)
    float dot  = __fadd_rn(__fadd_rn(__fmul_rn(mx,p.x), __fmul_rn(my,p.y)), __fmul_rn(mz,p.z));
    float dist = __fsub_rn(__fadd_rn(sqq, p.w), __fmul_rn(2.0f, dot));
    unsigned long long key = pack_key(dist, j);
    INS6(key);
  }

  if (c != 0) {
    int o = (c - 1) * 6;
    mk[qb][o+0]=k0; mk[qb][o+1]=k1; mk[qb][o+2]=k2;
    mk[qb][o+3]=k3; mk[qb][o+4]=k4; mk[qb][o+5]=k5;
  }
  __syncthreads();
  if (c == 0) {
#pragma unroll
    for (int t = 0; t < 18; ++t) {
      unsigned long long key = mk[qb][t];
      INS6(key);
    }
    knn_idx[q*6+0] = (int)(unsigned)k0;
    knn_idx[q*6+1] = (int)(unsigned)k1;
    knn_idx[q*6+2] = (int)(unsigned)k2;
    knn_idx[q*6+3] = (int)(unsigned)k3;
    knn_idx[q*6+4] = (int)(unsigned)k4;
    knn_idx[q*6+5] = (int)(unsigned)k5;
  }
}

// ---------------- fp32 tiled GEMM: C[m,n] = sum_k A[m,k]*B[n,k] (+R), row-major ----------------
__global__ __launch_bounds__(256) void gemm64(const float* __restrict__ A,
                                              const float* __restrict__ Bm,
                                              float* __restrict__ C,
                                              const float* __restrict__ R,
                                              int M, int N, int Kd,
                                              int lda, int ldb, int ldc) {
  __shared__ __align__(16) float As[32][64];
  __shared__ __align__(16) float Bs[32][64];
  int tid = threadIdx.x;
  int bm = blockIdx.x * 64, bn = blockIdx.y * 64;
  int tx = tid & 15, ty = tid >> 4;
  int arow = tid >> 3;     // 0..31
  int acol4 = tid & 7;     // float4 index 0..7

  float acc[4][4] = {};

  for (int k0 = 0; k0 < Kd; k0 += 32) {
    float4 a0 = *(const float4*)&A[(size_t)(bm + arow)      * lda + k0 + acol4*4];
    float4 a1 = *(const float4*)&A[(size_t)(bm + arow + 32) * lda + k0 + acol4*4];
    float4 b0 = *(const float4*)&Bm[(size_t)(bn + arow)      * ldb + k0 + acol4*4];
    float4 b1 = *(const float4*)&Bm[(size_t)(bn + arow + 32) * ldb + k0 + acol4*4];
    __syncthreads();
    As[acol4*4+0][arow] = a0.x; As[acol4*4+1][arow] = a0.y;
    As[acol4*4+2][arow] = a0.z; As[acol4*4+3][arow] = a0.w;
    As[acol4*4+0][arow+32] = a1.x; As[acol4*4+1][arow+32] = a1.y;
    As[acol4*4+2][arow+32] = a1.z; As[acol4*4+3][arow+32] = a1.w;
    Bs[acol4*4+0][arow] = b0.x; Bs[acol4*4+1][arow] = b0.y;
    Bs[acol4*4+2][arow] = b0.z; Bs[acol4*4+3][arow] = b0.w;
    Bs[acol4*4+0][arow+32] = b1.x; Bs[acol4*4+1][arow+32] = b1.y;
    Bs[acol4*4+2][arow+32] = b1.z; Bs[acol4*4+3][arow+32] = b1.w;
    __syncthreads();
#pragma unroll
    for (int kk = 0; kk < 32; ++kk) {
      float4 av = *(const float4*)&As[kk][ty*4];
      float4 bv = *(const float4*)&Bs[kk][tx*4];
      acc[0][0] += av.x*bv.x; acc[0][1] += av.x*bv.y; acc[0][2] += av.x*bv.z; acc[0][3] += av.x*bv.w;
      acc[1][0] += av.y*bv.x; acc[1][1] += av.y*bv.y; acc[1][2] += av.y*bv.z; acc[1][3] += av.y*bv.w;
      acc[2][0] += av.z*bv.x; acc[2][1] += av.z*bv.y; acc[2][2] += av.z*bv.z; acc[2][3] += av.z*bv.w;
      acc[3][0] += av.w*bv.x; acc[3][1] += av.w*bv.y; acc[3][2] += av.w*bv.z; acc[3][3] += av.w*bv.w;
    }
  }

#pragma unroll
  for (int i2 = 0; i2 < 4; ++i2) {
    int row = bm + ty*4 + i2;
    int col = bn + tx*4;
    float4 out;
    out.x = acc[i2][0]; out.y = acc[i2][1]; out.z = acc[i2][2]; out.w = acc[i2][3];
    if (R) {
      float4 rr = *(const float4*)&R[(size_t)row * ldc + col];
      out.x += rr.x; out.y += rr.y; out.z += rr.z; out.w += rr.w;
    }
    *(float4*)&C[(size_t)row * ldc + col] = out;
  }
}

// ---------------- per-point attention: one wave per point ----------------
__global__ __launch_bounds__(256) void attn_kernel(const float* __restrict__ XQKV,
                                                   const int* __restrict__ knn_idx,
                                                   float* __restrict__ attn_out,
                                                   float* __restrict__ xw_sum,
                                                   float* __restrict__ xw_cnt) {
  int p = blockIdx.x * 4 + (threadIdx.x >> 6);   // point id 0..32767
  int lane = threadIdx.x & 63;
  int b = p >> 13;                 // /8192
  size_t gbase = (size_t)b << 13;  // b*V
  size_t prow = (size_t)p * 768;

  float4 q4 = *(const float4*)&XQKV[prow + lane*4];
  float4 self4 = *(const float4*)&XQKV[prow + 512 + lane*4];

  int idx[KK];
#pragma unroll
  for (int j = 0; j < KK; ++j) idx[j] = knn_idx[p*KK + j];

  float4 k4[KK], v4[KK];
#pragma unroll
  for (int j = 0; j < KK; ++j) {
    size_t r = (gbase + idx[j]) * 768;
    k4[j] = *(const float4*)&XQKV[r + 256 + lane*4];
    v4[j] = *(const float4*)&XQKV[r + 512 + lane*4];
  }

  // scores: per-head dot over 32 dims (8 lanes/head, 4 dims/lane)
  float s[KK];
#pragma unroll
  for (int j = 0; j < KK; ++j) {
    float t = q4.x*k4[j].x + q4.y*k4[j].y + q4.z*k4[j].z + q4.w*k4[j].w;
    t += __shfl_xor(t, 1);
    t += __shfl_xor(t, 2);
    t += __shfl_xor(t, 4);
    s[j] = t * 0.17677669529663687f;   // 1/sqrt(32)
  }

  // softmax over K=6 (lane-local, uniform within head group)
  float m = s[0];
#pragma unroll
  for (int j = 1; j < KK; ++j) m = fmaxf(m, s[j]);
  float e[KK], denom = 0.f;
#pragma unroll
  for (int j = 0; j < KK; ++j) { e[j] = expf(s[j] - m); denom += e[j]; }
  float inv = 1.0f / denom;
#pragma unroll
  for (int j = 0; j < KK; ++j) e[j] *= inv;

  // output: sum_j attn_j * (XV[idx_j] - XV[self])
  float4 o = make_float4(0.f, 0.f, 0.f, 0.f);
#pragma unroll
  for (int j = 0; j < KK; ++j) {
    float a = e[j];
    o.x += a * (v4[j].x - self4.x);
    o.y += a * (v4[j].y - self4.y);
    o.z += a * (v4[j].z - self4.z);
    o.w += a * (v4[j].w - self4.w);
  }
  *(float4*)&attn_out[(size_t)p * 256 + lane*4] = o;

  // x_w scatter: mean over heads of attn, atomically accumulated at target index
#pragma unroll
  for (int j = 0; j < KK; ++j) {
    float t = e[j];
    t += __shfl_xor(t, 8);
    t += __shfl_xor(t, 16);
    t += __shfl_xor(t, 32);
    if (lane == 0) {
      atomicAdd(&xw_sum[gbase + idx[j]], t * 0.125f);
      atomicAdd(&xw_cnt[gbase + idx[j]], 1.0f);
    }
  }
}

// ---------------- finalize: xw_out = sum/(count+1) ----------------
__global__ void finalize_xw(const float* __restrict__ xw_sum,
                            const float* __restrict__ xw_cnt,
                            float* __restrict__ out) {
  int i = blockIdx.x * blockDim.x + threadIdx.x;
  if (i < NP) out[i] = xw_sum[i] / (xw_cnt[i] + 1.0f);
}

extern "C" void kernel_launch(void* const* d_in, const int* in_sizes, int n_in,
                              void* d_out, int out_size, void* d_ws, size_t ws_size,
                              hipStream_t stream) {
  const float* x     = (const float*)d_in[0];   // [B,V,E]
  const float* xv    = (const float*)d_in[1];   // [B,V,3]
  const float* w_in  = (const float*)d_in[2];   // [3E,E]
  const float* w_out = (const float*)d_in[3];   // [E,E]
  float* out = (float*)d_out;

  char* ws = (char*)d_ws;
  float4* xv4     = (float4*)(ws + OFF_XV4);
  int*    knn     = (int*)(ws + OFF_KNN);
  float*  xw_sum  = (float*)(ws + OFF_XWS);
  float*  xw_cnt  = (float*)(ws + OFF_XWC);
  float*  XQKV    = (float*)(ws + OFF_XQKV);
  float*  attn_o  = (float*)(ws + OFF_ATTN);

  prep_kernel<<<(NP + 255) / 256, 256, 0, stream>>>(xv, xv4, xw_sum, xw_cnt);
  knn_kernel<<<NP / 64, 256, 0, stream>>>(xv4, knn);
  // XQKV = x @ in_proj_w.T   [32768,768]
  gemm64<<<dim3(NP/64, 768/64), 256, 0, stream>>>(x, w_in, XQKV, nullptr,
                                                  NP, 768, EE, EE, EE, 768);
  attn_kernel<<<NP / 4, 256, 0, stream>>>(XQKV, knn, attn_o, xw_sum, xw_cnt);
  // x_out = attn_o @ out_proj_w.T + x   [32768,256]
  gemm64<<<dim3(NP/64, 256/64), 256, 0, stream>>>(attn_o, w_out, out, x,
                                                  NP, 256, EE, EE, EE, 256);
  finalize_xw<<<NP / 256, 256, 0, stream>>>(xw_sum, xw_cnt, out + (size_t)NP * EE);
}

// Round 4
// 281.351 us; speedup vs baseline: 2.4864x; 2.2834x over previous
//
#include <hip/hip_runtime.h>
#include <hip/hip_bf16.h>
#include <math.h>

// Problem constants
#define BB 4
#define VV 8192
#define EE 256
#define HH 8
#define KK 6
#define NP (BB*VV)          // 32768 points total

// ---------------- workspace layout (bytes), total ~86 MB ----------------
#define OFF_XV4 0            // float4[NP]            524288
#define OFF_KNN 524288       // int[NP*6]             786432
#define OFF_XWS 1310720      // float[NP]             131072
#define OFF_XWC 1441792      // float[NP]             131072
#define OFF_XB  1572864      // bf16[NP*256]          16777216
#define OFF_WB  18350080     // bf16[1024*256]        524288  (w_in 768 rows, w_out 256 rows)
#define OFF_QKV 18874368     // bf16[NP*768]          50331648
#define OFF_AO  69206016     // bf16[NP*256]          16777216 -> ends 85983232

typedef float f32x4 __attribute__((ext_vector_type(4)));
typedef __bf16 bf16x8 __attribute__((ext_vector_type(8)));

__device__ __forceinline__ unsigned short f2b(float f) {
  __hip_bfloat16 h = __float2bfloat16(f);
  return *reinterpret_cast<unsigned short*>(&h);
}
__device__ __forceinline__ float b2f(unsigned short u) {
  unsigned v = ((unsigned)u) << 16;
  return __uint_as_float(v);
}

// ---------------- prep: pack xyz+sq, zero scatter accumulators ----------------
__global__ void prep_kernel(const float* __restrict__ xv, float4* __restrict__ xv4,
                            float* __restrict__ xw_sum, float* __restrict__ xw_cnt) {
  int i = blockIdx.x * blockDim.x + threadIdx.x;
  if (i >= NP) return;
  float x0 = xv[i*3+0], x1 = xv[i*3+1], x2 = xv[i*3+2];
  // exact fp32 op order of the reference: ((x0*x0 + x1*x1) + x2*x2), no FMA contraction
  float sq = __fadd_rn(__fadd_rn(__fmul_rn(x0,x0), __fmul_rn(x1,x1)), __fmul_rn(x2,x2));
  xv4[i] = make_float4(x0, x1, x2, sq);
  xw_sum[i] = 0.f;
  xw_cnt[i] = 0.f;
}

// ---------------- f32 -> bf16 bulk convert (RNE) ----------------
__global__ void cvt_bf16(const float* __restrict__ src, unsigned short* __restrict__ dst, int n4) {
  int i = blockIdx.x * blockDim.x + threadIdx.x;
  if (i >= n4) return;
  float4 v = ((const float4*)src)[i];
  ushort4 o;
  o.x = f2b(v.x); o.y = f2b(v.y); o.z = f2b(v.z); o.w = f2b(v.w);
  ((ushort4*)dst)[i] = o;
}

// ---------------- brute-force KNN ----------------
// 32 queries/block, 8 chunks/query (tid = c*32 + qb). Candidates staged in LDS
// tiles of 1024. Per-lane stream of 1024 candidates with j strictly increasing,
// so a STRICT float compare chain implements lexicographic (dist, idx) exactly
// (equal-dist-later-index never displaces). Cross-chunk merge uses packed u64
// keys (sortable dist<<32 | idx) for exact tie-break in arbitrary j order.

__device__ __forceinline__ unsigned long long pack_key(float dist, int j) {
  unsigned du = __float_as_uint(dist);
  du ^= (unsigned)((int)du >> 31) | 0x80000000u;   // monotone float->uint map
  return ((unsigned long long)du << 32) | (unsigned)j;
}

#define INSU(key) \
  if (key < k5) { \
    bool b4 = key < k4, b3 = key < k3, b2 = key < k2, b1 = key < k1, b0 = key < k0; \
    k5 = b4 ? k4 : key; \
    k4 = b4 ? (b3 ? k3 : key) : k4; \
    k3 = b3 ? (b2 ? k2 : key) : k3; \
    k2 = b2 ? (b1 ? k1 : key) : k2; \
    k1 = b1 ? (b0 ? k0 : key) : k1; \
    k0 = b0 ? key : k0; \
  }

__global__ __launch_bounds__(256) void knn_kernel(const float4* __restrict__ xv4,
                                                  int* __restrict__ knn_idx) {
  __shared__ float4 tile[1024];                    // 16 KB, reused for merge keys
  int tid = threadIdx.x;
  int qb = tid & 31;
  int c = tid >> 5;                                // chunk 0..7
  int q = blockIdx.x * 32 + qb;
  int base = (q >> 13) << 13;                      // batch base (8192 % 32 == 0)

  float4 me = xv4[q];
  float mx = me.x, my = me.y, mz = me.z, sqq = me.w;

  float d0=INFINITY,d1=INFINITY,d2=INFINITY,d3=INFINITY,d4=INFINITY,d5=INFINITY;
  int   i0=0x7fffffff,i1=0x7fffffff,i2=0x7fffffff,i3=0x7fffffff,i4=0x7fffffff,i5=0x7fffffff;

  for (int t = 0; t < 8; ++t) {
    __syncthreads();
#pragma unroll
    for (int u = 0; u < 4; ++u)
      tile[tid + u*256] = xv4[base + t*1024 + tid + u*256];
    __syncthreads();

    const float4* cp = &tile[c * 128];
    int jbase = t*1024 + c*128;
#pragma unroll 8
    for (int it = 0; it < 128; ++it) {
      float4 p = cp[it];
      // reference fp32 semantics: d = (sq_v + sq_w) - 2*dot, dot = ((x0*y0 + x1*y1) + x2*y2)
      float dot  = __fadd_rn(__fadd_rn(__fmul_rn(mx,p.x), __fmul_rn(my,p.y)), __fmul_rn(mz,p.z));
      float dist = __fsub_rn(__fadd_rn(sqq, p.w), __fmul_rn(2.0f, dot));
      if (dist < d5) {
        int j = jbase + it;
        bool b4 = dist < d4, b3 = dist < d3, b2 = dist < d2, b1 = dist < d1, b0 = dist < d0;
        d5 = b4 ? d4 : dist;            i5 = b4 ? i4 : j;
        d4 = b4 ? (b3 ? d3 : dist) : d4; i4 = b4 ? (b3 ? i3 : j) : i4;
        d3 = b3 ? (b2 ? d2 : dist) : d3; i3 = b3 ? (b2 ? i2 : j) : i3;
        d2 = b2 ? (b1 ? d1 : dist) : d2; i2 = b2 ? (b1 ? i1 : j) : i2;
        d1 = b1 ? (b0 ? d0 : dist) : d1; i1 = b1 ? (b0 ? i0 : j) : i1;
        d0 = b0 ? dist : d0;            i0 = b0 ? j : i0;
      }
    }
  }

  __syncthreads();   // tile reads done; safe to alias as merge buffer
  unsigned long long* mk = reinterpret_cast<unsigned long long*>(tile);  // mk[qb*43 + s]
  if (c > 0) {
    int o = qb*43 + (c-1)*6;
    mk[o+0]=pack_key(d0,i0); mk[o+1]=pack_key(d1,i1); mk[o+2]=pack_key(d2,i2);
    mk[o+3]=pack_key(d3,i3); mk[o+4]=pack_key(d4,i4); mk[o+5]=pack_key(d5,i5);
  }
  __syncthreads();
  if (c == 0) {
    unsigned long long k0=pack_key(d0,i0),k1=pack_key(d1,i1),k2=pack_key(d2,i2),
                       k3=pack_key(d3,i3),k4=pack_key(d4,i4),k5=pack_key(d5,i5);
    for (int s = 0; s < 42; ++s) {
      unsigned long long key = mk[qb*43 + s];
      INSU(key);
    }
    knn_idx[q*6+0] = (int)(unsigned)k0;
    knn_idx[q*6+1] = (int)(unsigned)k1;
    knn_idx[q*6+2] = (int)(unsigned)k2;
    knn_idx[q*6+3] = (int)(unsigned)k3;
    knn_idx[q*6+4] = (int)(unsigned)k4;
    knn_idx[q*6+5] = (int)(unsigned)k5;
  }
}

// ---------------- bf16 MFMA GEMM: C[m,n] = sum_k A[m,k]*B[n,k], K=256 ----------------
// 128x128 tile, BK=32, 4 waves (each 64x64 quadrant, 4x4 16x16 fragments),
// global_load_lds width-16 staging, m97 2-barrier structure.
template<bool OUT_BF16>
__global__ __launch_bounds__(256) void gemm_bf16(const unsigned short* __restrict__ A,
                                                 const unsigned short* __restrict__ Bw,
                                                 void* __restrict__ Cv,
                                                 const float* __restrict__ R,
                                                 int ldc) {
  __shared__ unsigned short ABs[8192];   // A tile [0,4096), B tile [4096,8192) ushort units
  int tid = threadIdx.x;
  int lane = tid & 63;
  int w = tid >> 6;
  int bm = blockIdx.x * 128;
  int bn = blockIdx.y * 128;
  int wr = w >> 1, wc = w & 1;

  f32x4 acc[4][4] = {};

  for (int ks = 0; ks < 8; ++ks) {
    int k0 = ks * 32;
    __syncthreads();
#pragma unroll
    for (int t = 0; t < 4; ++t) {
      int bg = (t*4 + w) * 64;           // wave-uniform granule base
      int g = bg + lane;
      const unsigned short* src;
      if (bg < 512) {                    // A granules
        int r = g >> 2, kb = g & 3;
        src = A + (size_t)(bm + r) * 256 + k0 + kb*8;
      } else {                           // B granules
        int g2 = g - 512;
        int r = g2 >> 2, kb = g2 & 3;
        src = Bw + (size_t)(bn + r) * 256 + k0 + kb*8;
      }
      __builtin_amdgcn_global_load_lds(
        (const __attribute__((address_space(1))) unsigned int*)src,
        (__attribute__((address_space(3))) unsigned int*)&ABs[bg*8],
        16, 0, 0);
    }
    __syncthreads();

    bf16x8 af[4], bfr[4];
#pragma unroll
    for (int m = 0; m < 4; ++m)
      af[m] = *(const bf16x8*)&ABs[(wr*64 + m*16 + (lane&15))*32 + (lane>>4)*8];
#pragma unroll
    for (int n = 0; n < 4; ++n)
      bfr[n] = *(const bf16x8*)&ABs[4096 + (wc*64 + n*16 + (lane&15))*32 + (lane>>4)*8];
#pragma unroll
    for (int m = 0; m < 4; ++m)
#pragma unroll
      for (int n = 0; n < 4; ++n)
        acc[m][n] = __builtin_amdgcn_mfma_f32_16x16x32_bf16(af[m], bfr[n], acc[m][n], 0, 0, 0);
  }

  int rb = bm + wr*64 + (lane>>4)*4;
  int cb = bn + wc*64 + (lane&15);
#pragma unroll
  for (int m = 0; m < 4; ++m)
#pragma unroll
    for (int n = 0; n < 4; ++n)
#pragma unroll
      for (int i = 0; i < 4; ++i) {
        int row = rb + m*16 + i;
        int col = cb + n*16;
        float v = acc[m][n][i];
        if (OUT_BF16) {
          ((unsigned short*)Cv)[(size_t)row*ldc + col] = f2b(v);
        } else {
          ((float*)Cv)[(size_t)row*ldc + col] = v + R[(size_t)row*ldc + col];
        }
      }
}

// ---------------- per-point attention: one wave per point (bf16 QKV) ----------------
__global__ __launch_bounds__(256) void attn_kernel(const unsigned short* __restrict__ QKV,
                                                   const int* __restrict__ knn_idx,
                                                   unsigned short* __restrict__ attn_out,
                                                   float* __restrict__ xw_sum,
                                                   float* __restrict__ xw_cnt) {
  int p = blockIdx.x * 4 + (threadIdx.x >> 6);   // point id
  int lane = threadIdx.x & 63;
  size_t gbase = (size_t)(p >> 13) << 13;        // batch base
  size_t prow = (size_t)p * 768;

  ushort4 qv = *(const ushort4*)&QKV[prow + lane*4];
  ushort4 sv = *(const ushort4*)&QKV[prow + 512 + lane*4];
  float qx=b2f(qv.x), qy=b2f(qv.y), qz=b2f(qv.z), qw=b2f(qv.w);
  float sx=b2f(sv.x), sy=b2f(sv.y), sz=b2f(sv.z), sw=b2f(sv.w);

  int idx[KK];
#pragma unroll
  for (int j = 0; j < KK; ++j) idx[j] = knn_idx[p*KK + j];

  float s[KK];
  float vx[KK], vy[KK], vz[KK], vw[KK];
#pragma unroll
  for (int j = 0; j < KK; ++j) {
    size_t r = (gbase + idx[j]) * 768;
    ushort4 kv = *(const ushort4*)&QKV[r + 256 + lane*4];
    ushort4 vv = *(const ushort4*)&QKV[r + 512 + lane*4];
    float t = qx*b2f(kv.x) + qy*b2f(kv.y) + qz*b2f(kv.z) + qw*b2f(kv.w);
    t += __shfl_xor(t, 1);
    t += __shfl_xor(t, 2);
    t += __shfl_xor(t, 4);
    s[j] = t * 0.17677669529663687f;   // 1/sqrt(32)
    vx[j] = b2f(vv.x); vy[j] = b2f(vv.y); vz[j] = b2f(vv.z); vw[j] = b2f(vv.w);
  }

  float m = s[0];
#pragma unroll
  for (int j = 1; j < KK; ++j) m = fmaxf(m, s[j]);
  float e[KK], denom = 0.f;
#pragma unroll
  for (int j = 0; j < KK; ++j) { e[j] = expf(s[j] - m); denom += e[j]; }
  float inv = 1.0f / denom;
#pragma unroll
  for (int j = 0; j < KK; ++j) e[j] *= inv;

  float ox=0.f, oy=0.f, oz=0.f, ow=0.f;
#pragma unroll
  for (int j = 0; j < KK; ++j) {
    float a = e[j];
    ox += a * (vx[j] - sx);
    oy += a * (vy[j] - sy);
    oz += a * (vz[j] - sz);
    ow += a * (vw[j] - sw);
  }
  ushort4 ov;
  ov.x = f2b(ox); ov.y = f2b(oy); ov.z = f2b(oz); ov.w = f2b(ow);
  *(ushort4*)&attn_out[(size_t)p * 256 + lane*4] = ov;

  // x_w scatter: mean over heads (orbit of xor{8,16,32} = one lane per head)
#pragma unroll
  for (int j = 0; j < KK; ++j) {
    float t = e[j];
    t += __shfl_xor(t, 8);
    t += __shfl_xor(t, 16);
    t += __shfl_xor(t, 32);
    if (lane == 0) {
      atomicAdd(&xw_sum[gbase + idx[j]], t * 0.125f);
      atomicAdd(&xw_cnt[gbase + idx[j]], 1.0f);
    }
  }
}

// ---------------- finalize: xw_out = sum/(count+1) ----------------
__global__ void finalize_xw(const float* __restrict__ xw_sum,
                            const float* __restrict__ xw_cnt,
                            float* __restrict__ out) {
  int i = blockIdx.x * blockDim.x + threadIdx.x;
  if (i < NP) out[i] = xw_sum[i] / (xw_cnt[i] + 1.0f);
}

extern "C" void kernel_launch(void* const* d_in, const int* in_sizes, int n_in,
                              void* d_out, int out_size, void* d_ws, size_t ws_size,
                              hipStream_t stream) {
  const float* x     = (const float*)d_in[0];   // [B,V,E]
  const float* xv    = (const float*)d_in[1];   // [B,V,3]
  const float* w_in  = (const float*)d_in[2];   // [3E,E]
  const float* w_out = (const float*)d_in[3];   // [E,E]
  float* out = (float*)d_out;

  char* ws = (char*)d_ws;
  float4*         xv4    = (float4*)(ws + OFF_XV4);
  int*            knn    = (int*)(ws + OFF_KNN);
  float*          xw_sum = (float*)(ws + OFF_XWS);
  float*          xw_cnt = (float*)(ws + OFF_XWC);
  unsigned short* xb     = (unsigned short*)(ws + OFF_XB);
  unsigned short* wb     = (unsigned short*)(ws + OFF_WB);
  unsigned short* qkv    = (unsigned short*)(ws + OFF_QKV);
  unsigned short* ao     = (unsigned short*)(ws + OFF_AO);

  prep_kernel<<<(NP + 255) / 256, 256, 0, stream>>>(xv, xv4, xw_sum, xw_cnt);
  cvt_bf16<<<(NP*256/4 + 255)/256, 256, 0, stream>>>(x, xb, NP*256/4);
  cvt_bf16<<<(768*256/4 + 255)/256, 256, 0, stream>>>(w_in, wb, 768*256/4);
  cvt_bf16<<<(256*256/4 + 255)/256, 256, 0, stream>>>(w_out, wb + 768*256, 256*256/4);

  knn_kernel<<<NP / 32, 256, 0, stream>>>(xv4, knn);

  // QKV = x @ in_proj_w.T   [32768,768] bf16
  gemm_bf16<true><<<dim3(NP/128, 768/128), 256, 0, stream>>>(xb, wb, qkv, nullptr, 768);

  attn_kernel<<<NP / 4, 256, 0, stream>>>(qkv, knn, ao, xw_sum, xw_cnt);

  // x_out = attn_o @ out_proj_w.T + x   [32768,256] f32
  gemm_bf16<false><<<dim3(NP/128, 256/128), 256, 0, stream>>>(ao, wb + 768*256, out, x, 256);

  finalize_xw<<<NP / 256, 256, 0, stream>>>(xw_sum, xw_cnt, out + (size_t)NP * EE);
}